// Round 3
// baseline (365.993 us; speedup 1.0000x reference)
//
#include <hip/hip_runtime.h>

#define B_ 32
#define T_ 4096
#define C_ 256
#define R_ (B_*T_)
#define H1_ 128
#define H2_ 64

#define TB 32   // timestep rows per block in kernel 1

// output layout (floats), concatenated in reference return order
#define PROBS_OFF 0
#define TS_OFF  (R_*4)
#define SEG_OFF (TS_OFF + R_)
#define MI_OFF  (SEG_OFF + R_)
#define MC_OFF  (MI_OFF + R_)

// LDS: single 8448-float region (33.8 KB) -> 4 blocks/CU.
//   Phase 1 (GEMM1): W1 chunk [64][132]
//   Phase 2+: H1 [32][132] at 0, H2 [32][68] at 4224, W3T [4][68] at 6400
#define W1S_OFF 0
#define W1S_P   132
#define H1S_OFF 0
#define H1S_P   132
#define H2S_OFF 4224
#define H2S_P   68
#define W3S_OFF 6400
#define W3S_P   68
#define SMEMF   8448

__device__ __forceinline__ void fma4(float4& a, float s, const float4& b) {
  a.x = fmaf(s, b.x, a.x); a.y = fmaf(s, b.y, a.y);
  a.z = fmaf(s, b.z, a.z); a.w = fmaf(s, b.w, a.w);
}

__global__ __launch_bounds__(256, 4) void mlp_conv_kernel(
    const float* __restrict__ X, const float* __restrict__ W1, const float* __restrict__ b1,
    const float* __restrict__ W2, const float* __restrict__ b2,
    const float* __restrict__ W3, const float* __restrict__ b3,
    const float* __restrict__ CW, const float* __restrict__ CB,
    float* __restrict__ out)
{
  __shared__ float sm[SMEMF];
  const int tid  = threadIdx.x;
  const int row0 = blockIdx.x * TB;

  // ---- conv1d (C->1, k=3, SAME over T) + sigmoid -> transition_scores ----
  // Reads X straight from global (also warms L1 for GEMM1's A reads).
  {
    const int row = tid >> 3, p = tid & 7;        // 32 rows x 8 partials
    const int grow = row0 + row;
    const int tb = grow & (T_ - 1);               // t within its batch row
    const float* x0p = X + (size_t)grow * C_;
    float s = 0.f;
    #pragma unroll
    for (int cc = 0; cc < 8; ++cc) {
      const int c = p * 32 + cc * 4;
      float4 x0 = *(const float4*)&x0p[c];
      float4 xm, xp;
      if (tb == 0)        xm = make_float4(0.f, 0.f, 0.f, 0.f);
      else                xm = *(const float4*)&x0p[c - C_];
      if (tb == T_ - 1)   xp = make_float4(0.f, 0.f, 0.f, 0.f);
      else                xp = *(const float4*)&x0p[c + C_];
      // conv_w flat layout: [c][k], k=0->x[t-1], 1->x[t], 2->x[t+1]
      float4 wa = *(const float4*)&CW[c * 3 + 0];
      float4 wb = *(const float4*)&CW[c * 3 + 4];
      float4 wc = *(const float4*)&CW[c * 3 + 8];
      s += xm.x * wa.x + x0.x * wa.y + xp.x * wa.z;
      s += xm.y * wa.w + x0.y * wb.x + xp.y * wb.y;
      s += xm.z * wb.z + x0.z * wb.w + xp.z * wc.x;
      s += xm.w * wc.y + x0.w * wc.z + xp.w * wc.w;
    }
    s += __shfl_xor(s, 1);
    s += __shfl_xor(s, 2);
    s += __shfl_xor(s, 4);
    if (p == 0) out[TS_OFF + grow] = 1.f / (1.f + expf(-(s + CB[0])));
  }

  // ---- GEMM1: (32x256)@(256x128), 4x4 per thread.
  //      A: wave-broadcast global loads (each X element read once per block),
  //         1-deep register prefetch. B: W1 staged in LDS, 64-k chunks. ----
  const int rt = tid >> 5, ct = tid & 31;   // 8 row-groups x 32 col-groups
  const int rb = rt * 4;
  const float* xr0 = X + (size_t)(row0 + rb + 0) * C_;
  const float* xr1 = X + (size_t)(row0 + rb + 1) * C_;
  const float* xr2 = X + (size_t)(row0 + rb + 2) * C_;
  const float* xr3 = X + (size_t)(row0 + rb + 3) * C_;
  float4 acc0 = make_float4(0.f, 0.f, 0.f, 0.f);
  float4 acc1 = acc0, acc2 = acc0, acc3 = acc0;
  float4 Ac0 = *(const float4*)&xr0[0];
  float4 Ac1 = *(const float4*)&xr1[0];
  float4 Ac2 = *(const float4*)&xr2[0];
  float4 Ac3 = *(const float4*)&xr3[0];
  for (int kc = 0; kc < 4; ++kc) {
    if (kc) __syncthreads();                 // prev chunk reads done
    #pragma unroll
    for (int i2 = 0; i2 < 8; ++i2) {
      int g = tid + 256 * i2;                // 64 rows x 32 f4
      int k = g >> 5, m = g & 31;
      float4 v = *(const float4*)&W1[(size_t)(kc * 64 + k) * H1_ + m * 4];
      *(float4*)&sm[W1S_OFF + k * W1S_P + m * 4] = v;
    }
    __syncthreads();
    #pragma unroll
    for (int k4 = 0; k4 < 16; ++k4) {
      const int kb = kc * 64 + k4 * 4;
      const int kn = (kb < 252) ? kb + 4 : 252;   // guard: last iter reloads (discarded)
      float4 An0 = *(const float4*)&xr0[kn];
      float4 An1 = *(const float4*)&xr1[kn];
      float4 An2 = *(const float4*)&xr2[kn];
      float4 An3 = *(const float4*)&xr3[kn];
      float4 q0 = *(const float4*)&sm[W1S_OFF + (k4 * 4 + 0) * W1S_P + ct * 4];
      float4 q1 = *(const float4*)&sm[W1S_OFF + (k4 * 4 + 1) * W1S_P + ct * 4];
      float4 q2 = *(const float4*)&sm[W1S_OFF + (k4 * 4 + 2) * W1S_P + ct * 4];
      float4 q3 = *(const float4*)&sm[W1S_OFF + (k4 * 4 + 3) * W1S_P + ct * 4];
      fma4(acc0, Ac0.x, q0); fma4(acc0, Ac0.y, q1); fma4(acc0, Ac0.z, q2); fma4(acc0, Ac0.w, q3);
      fma4(acc1, Ac1.x, q0); fma4(acc1, Ac1.y, q1); fma4(acc1, Ac1.z, q2); fma4(acc1, Ac1.w, q3);
      fma4(acc2, Ac2.x, q0); fma4(acc2, Ac2.y, q1); fma4(acc2, Ac2.z, q2); fma4(acc2, Ac2.w, q3);
      fma4(acc3, Ac3.x, q0); fma4(acc3, Ac3.y, q1); fma4(acc3, Ac3.z, q2); fma4(acc3, Ac3.w, q3);
      Ac0 = An0; Ac1 = An1; Ac2 = An2; Ac3 = An3;
    }
  }
  __syncthreads();   // all W1S reads done; safe to overlay H1/H2/W3T

  // ---- bias+relu -> H1s (overlays W1S) ----
  {
    float4 bb = *(const float4*)&b1[ct * 4];
    float4 h;
    h = acc0; h.x = fmaxf(h.x + bb.x, 0.f); h.y = fmaxf(h.y + bb.y, 0.f);
              h.z = fmaxf(h.z + bb.z, 0.f); h.w = fmaxf(h.w + bb.w, 0.f);
    *(float4*)&sm[H1S_OFF + (rb + 0) * H1S_P + ct * 4] = h;
    h = acc1; h.x = fmaxf(h.x + bb.x, 0.f); h.y = fmaxf(h.y + bb.y, 0.f);
              h.z = fmaxf(h.z + bb.z, 0.f); h.w = fmaxf(h.w + bb.w, 0.f);
    *(float4*)&sm[H1S_OFF + (rb + 1) * H1S_P + ct * 4] = h;
    h = acc2; h.x = fmaxf(h.x + bb.x, 0.f); h.y = fmaxf(h.y + bb.y, 0.f);
              h.z = fmaxf(h.z + bb.z, 0.f); h.w = fmaxf(h.w + bb.w, 0.f);
    *(float4*)&sm[H1S_OFF + (rb + 2) * H1S_P + ct * 4] = h;
    h = acc3; h.x = fmaxf(h.x + bb.x, 0.f); h.y = fmaxf(h.y + bb.y, 0.f);
              h.z = fmaxf(h.z + bb.z, 0.f); h.w = fmaxf(h.w + bb.w, 0.f);
    *(float4*)&sm[H1S_OFF + (rb + 3) * H1S_P + ct * 4] = h;
  }
  __syncthreads();

  // ---- GEMM2: (32x128)@(128x64), 2x4 per thread.
  //      A: H1 LDS broadcast. B: W2 from global (L2-hot) with 1-deep prefetch. ----
  {
    const int rt2 = tid >> 4, ct2 = tid & 15;
    const float* w2p = W2 + ct2 * 4;
    float4 Wc0 = *(const float4*)&w2p[0 * H2_];
    float4 Wc1 = *(const float4*)&w2p[1 * H2_];
    float4 Wc2 = *(const float4*)&w2p[2 * H2_];
    float4 Wc3 = *(const float4*)&w2p[3 * H2_];
    float4 c0 = make_float4(0.f, 0.f, 0.f, 0.f), c1 = c0;
    #pragma unroll
    for (int k4 = 0; k4 < 32; ++k4) {
      const int rn = (k4 < 31) ? (k4 + 1) * 4 : k4 * 4;  // guard: last reloads
      float4 Wn0 = *(const float4*)&w2p[(rn + 0) * H2_];
      float4 Wn1 = *(const float4*)&w2p[(rn + 1) * H2_];
      float4 Wn2 = *(const float4*)&w2p[(rn + 2) * H2_];
      float4 Wn3 = *(const float4*)&w2p[(rn + 3) * H2_];
      float4 a0 = *(const float4*)&sm[H1S_OFF + (rt2 * 2 + 0) * H1S_P + k4 * 4];
      float4 a1 = *(const float4*)&sm[H1S_OFF + (rt2 * 2 + 1) * H1S_P + k4 * 4];
      fma4(c0, a0.x, Wc0); fma4(c0, a0.y, Wc1); fma4(c0, a0.z, Wc2); fma4(c0, a0.w, Wc3);
      fma4(c1, a1.x, Wc0); fma4(c1, a1.y, Wc1); fma4(c1, a1.z, Wc2); fma4(c1, a1.w, Wc3);
      Wc0 = Wn0; Wc1 = Wn1; Wc2 = Wn2; Wc3 = Wn3;
    }
    float4 bb = *(const float4*)&b2[ct2 * 4];
    c0.x = fmaxf(c0.x + bb.x, 0.f); c0.y = fmaxf(c0.y + bb.y, 0.f);
    c0.z = fmaxf(c0.z + bb.z, 0.f); c0.w = fmaxf(c0.w + bb.w, 0.f);
    c1.x = fmaxf(c1.x + bb.x, 0.f); c1.y = fmaxf(c1.y + bb.y, 0.f);
    c1.z = fmaxf(c1.z + bb.z, 0.f); c1.w = fmaxf(c1.w + bb.w, 0.f);
    *(float4*)&sm[H2S_OFF + (rt2 * 2 + 0) * H2S_P + ct2 * 4] = c0;
    *(float4*)&sm[H2S_OFF + (rt2 * 2 + 1) * H2S_P + ct2 * 4] = c1;
  }
  { // W3 (64x4) -> W3T[4][64]
    int k = tid >> 2, j = tid & 3;
    sm[W3S_OFF + j * W3S_P + k] = W3[tid];
  }
  __syncthreads();

  // ---- GEMM3 (64->4) + softmax + dom/conf ----
  if (tid < 128) {
    const int row = tid >> 2, j = tid & 3;
    float4 ps = make_float4(0.f, 0.f, 0.f, 0.f);
    #pragma unroll
    for (int k4 = 0; k4 < 16; ++k4) {
      float4 a = *(const float4*)&sm[H2S_OFF + row * H2S_P + k4 * 4];
      float4 w = *(const float4*)&sm[W3S_OFF + j * W3S_P + k4 * 4];
      ps.x = fmaf(a.x, w.x, ps.x);
      ps.y = fmaf(a.y, w.y, ps.y);
      ps.z = fmaf(a.z, w.z, ps.z);
      ps.w = fmaf(a.w, w.w, ps.w);
    }
    float l = ((ps.x + ps.y) + (ps.z + ps.w)) + b3[j];
    float n1v = __shfl_xor(l, 1);
    float n2v = __shfl_xor(l, 2);
    float n3v = __shfl_xor(l, 3);
    // reconstruct logits indexed 0..3 (value at index i came from lane j^m, m=i^j)
    float L0 = (j == 0) ? l : (j == 1) ? n1v : (j == 2) ? n2v : n3v;
    float L1 = (j == 1) ? l : (j == 0) ? n1v : (j == 2) ? n3v : n2v;
    float L2 = (j == 2) ? l : (j == 0) ? n2v : (j == 1) ? n3v : n1v;
    float L3 = (j == 3) ? l : (j == 0) ? n3v : (j == 1) ? n2v : n1v;
    float mx = fmaxf(fmaxf(L0, L1), fmaxf(L2, L3));
    float e0 = expf(L0 - mx), e1 = expf(L1 - mx), e2 = expf(L2 - mx), e3 = expf(L3 - mx);
    float inv = 1.f / ((e0 + e1) + (e2 + e3));
    float p0 = e0 * inv, p1 = e1 * inv, p2 = e2 * inv, p3 = e3 * inv;
    const int grow = row0 + row;
    float pown = (j == 0) ? p0 : (j == 1) ? p1 : (j == 2) ? p2 : p3;
    out[PROBS_OFF + (size_t)grow * 4 + j] = pown;
    if (j == 0) {
      int dom = 0; float pm = p0;
      if (p1 > pm) { pm = p1; dom = 1; }
      if (p2 > pm) { pm = p2; dom = 2; }
      if (p3 > pm) { pm = p3; dom = 3; }
      out[MI_OFF + grow] = (float)dom;   // park dom for kernel 2
      out[MC_OFF + grow] = pm;           // park conf for kernel 2
    }
  }
}

// ---- kernel 2: per-batch-row segmentation + segment means ----
__global__ __launch_bounds__(1024, 1) void seg_kernel(
    const float* __restrict__ inten, float* __restrict__ out)
{
  __shared__ float scnt[T_], ssi[T_], ssc[T_];
  __shared__ int wtot[16], wexcl[16];
  const int tid = threadIdx.x;
  const int lane = tid & 63, wid = tid >> 6;
  const size_t base = (size_t)blockIdx.x * T_;
  const float* tsS = out + TS_OFF;
  float* segO = out + SEG_OFF;
  float* miO  = out + MI_OFF;
  float* mcO  = out + MC_OFF;
  const int t4 = tid * 4;

  float4 dv = *(const float4*)&miO[base + t4];        // dom (as float)
  float4 tv = *(const float4*)&tsS[base + t4];        // transition scores
  float4 iv = *(const float4*)&inten[base + t4];      // intensity
  float4 cv = *(const float4*)&mcO[base + t4];        // confidence
  float pd = (tid == 0) ? 0.f : miO[base + t4 - 1];

  for (int i = tid; i < T_; i += 1024) { scnt[i] = 0.f; ssi[i] = 0.f; ssc[i] = 0.f; }

  int c0 = (t4 == 0) ? 0 : (((dv.x != pd)   || (tv.x > 0.7f)) ? 1 : 0);
  int c1 = ((dv.y != dv.x) || (tv.y > 0.7f)) ? 1 : 0;
  int c2 = ((dv.z != dv.y) || (tv.z > 0.7f)) ? 1 : 0;
  int c3 = ((dv.w != dv.z) || (tv.w > 0.7f)) ? 1 : 0;
  int l0 = c0, l1 = c0 + c1, l2 = l1 + c2, l3 = l2 + c3;
  const int tsum = l3;

  // wave-inclusive scan of per-thread sums
  int v = tsum;
  #pragma unroll
  for (int d = 1; d < 64; d <<= 1) {
    int o = __shfl_up(v, (unsigned)d);
    if (lane >= d) v += o;
  }
  if (lane == 63) wtot[wid] = v;
  __syncthreads();
  if (tid < 16) {
    int x = wtot[tid];
    int xx = x;
    #pragma unroll
    for (int d = 1; d < 16; d <<= 1) {
      int o = __shfl_up(xx, (unsigned)d);
      if (tid >= d) xx += o;
    }
    wexcl[tid] = xx - x;   // exclusive wave offset
  }
  __syncthreads();
  const int texcl = wexcl[wid] + (v - tsum);
  const int s0 = texcl + l0, s1 = texcl + l1, s2 = texcl + l2, s3 = texcl + l3;

  // merged LDS atomics for segment sums
  {
    int cur = s0; float aI = iv.x, aC = cv.x, aN = 1.f;
    if (s1 == cur) { aI += iv.y; aC += cv.y; aN += 1.f; }
    else { atomicAdd(&ssi[cur], aI); atomicAdd(&ssc[cur], aC); atomicAdd(&scnt[cur], aN);
           cur = s1; aI = iv.y; aC = cv.y; aN = 1.f; }
    if (s2 == cur) { aI += iv.z; aC += cv.z; aN += 1.f; }
    else { atomicAdd(&ssi[cur], aI); atomicAdd(&ssc[cur], aC); atomicAdd(&scnt[cur], aN);
           cur = s2; aI = iv.z; aC = cv.z; aN = 1.f; }
    if (s3 == cur) { aI += iv.w; aC += cv.w; aN += 1.f; }
    else { atomicAdd(&ssi[cur], aI); atomicAdd(&ssc[cur], aC); atomicAdd(&scnt[cur], aN);
           cur = s3; aI = iv.w; aC = cv.w; aN = 1.f; }
    atomicAdd(&ssi[cur], aI); atomicAdd(&ssc[cur], aC); atomicAdd(&scnt[cur], aN);
  }
  __syncthreads();

  float n0 = scnt[s0], n1 = scnt[s1], n2 = scnt[s2], n3 = scnt[s3];
  float4 m4, q4, g4;
  m4.x = ssi[s0] / n0; m4.y = ssi[s1] / n1; m4.z = ssi[s2] / n2; m4.w = ssi[s3] / n3;
  q4.x = ssc[s0] / n0; q4.y = ssc[s1] / n1; q4.z = ssc[s2] / n2; q4.w = ssc[s3] / n3;
  g4.x = (float)s0; g4.y = (float)s1; g4.z = (float)s2; g4.w = (float)s3;
  *(float4*)&segO[base + t4] = g4;
  *(float4*)&miO[base + t4]  = m4;
  *(float4*)&mcO[base + t4]  = q4;
}

extern "C" void kernel_launch(void* const* d_in, const int* in_sizes, int n_in,
                              void* d_out, int out_size, void* d_ws, size_t ws_size,
                              hipStream_t stream) {
  (void)in_sizes; (void)n_in; (void)out_size; (void)d_ws; (void)ws_size;
  const float* X   = (const float*)d_in[0];
  const float* INT = (const float*)d_in[1];
  const float* W1  = (const float*)d_in[2];
  const float* B1  = (const float*)d_in[3];
  const float* W2  = (const float*)d_in[4];
  const float* B2  = (const float*)d_in[5];
  const float* W3  = (const float*)d_in[6];
  const float* B3  = (const float*)d_in[7];
  const float* CW  = (const float*)d_in[8];
  const float* CB  = (const float*)d_in[9];
  float* out = (float*)d_out;

  hipLaunchKernelGGL(mlp_conv_kernel, dim3(R_ / TB), dim3(256), 0, stream,
                     X, W1, B1, W2, B2, W3, B3, CW, CB, out);
  hipLaunchKernelGGL(seg_kernel, dim3(B_), dim3(1024), 0, stream, INT, out);
}

// Round 4
// 205.760 us; speedup vs baseline: 1.7787x; 1.7787x over previous
//
#include <hip/hip_runtime.h>

#define B_ 32
#define T_ 4096
#define C_ 256
#define R_ (B_*T_)
#define H1_ 128
#define H2_ 64

#define TB 32   // timestep rows per block in kernel 1

// output layout (floats), concatenated in reference return order
#define PROBS_OFF 0
#define TS_OFF  (R_*4)
#define SEG_OFF (TS_OFF + R_)
#define MI_OFF  (SEG_OFF + R_)
#define MC_OFF  (MI_OFF + R_)

// LDS float layout, 12544 floats = 50.2 KB -> 3 blocks/CU:
//   XS  [32][260] at 0       (X tile; overlaid by H2S/W3S after GEMM1)
//   W1S [32][128] at 8320    (linear chunk; overlaid by H1S after GEMM1)
#define XS_OFF  0
#define XS_P    260
#define W1S_OFF 8320          // linear [32][128]
#define H1S_OFF 8320          // [32][132]
#define H1S_P   132
#define H2S_OFF 0             // [32][68]  (overlays XS)
#define H2S_P   68
#define W3S_OFF 2176          // [4][68]   (overlays XS)
#define W3S_P   68
#define SMEMF   12544

__device__ __forceinline__ void fma4(float4& a, float s, const float4& b) {
  a.x = fmaf(s, b.x, a.x); a.y = fmaf(s, b.y, a.y);
  a.z = fmaf(s, b.z, a.z); a.w = fmaf(s, b.w, a.w);
}

__global__ __launch_bounds__(256, 4) void mlp_conv_kernel(
    const float* __restrict__ X, const float* __restrict__ W1, const float* __restrict__ b1,
    const float* __restrict__ W2, const float* __restrict__ b2,
    const float* __restrict__ W3, const float* __restrict__ b3,
    const float* __restrict__ CW, const float* __restrict__ CB,
    float* __restrict__ out)
{
  __shared__ float sm[SMEMF];
  const int tid  = threadIdx.x;
  const int row0 = blockIdx.x * TB;

  // ---- W1 chunk 0 prefetch (regs) — issued before XS staging barrier ----
  float4 st0 = *(const float4*)&W1[0 * 1024 + tid * 4];
  float4 st1 = *(const float4*)&W1[1 * 1024 + tid * 4];
  float4 st2 = *(const float4*)&W1[2 * 1024 + tid * 4];
  float4 st3 = *(const float4*)&W1[3 * 1024 + tid * 4];

  // ---- stage X tile (32 rows x 256) into padded LDS ----
  #pragma unroll
  for (int i2 = 0; i2 < 8; ++i2) {
    int g = tid + 256 * i2;          // f4 index: 32*64 = 2048 total
    int r = g >> 6, m = g & 63;
    float4 v = *(const float4*)&X[(size_t)(row0 + r) * C_ + m * 4];
    *(float4*)&sm[XS_OFF + r * XS_P + m * 4] = v;
  }
  __syncthreads();

  // ---- conv1d (C->1, k=3, SAME over T) + sigmoid -> transition_scores ----
  // lane mapping: row = w*8 + (l&7), partial p = l>>3 -> 2-way LDS conflicts max
  {
    const int l = tid & 63, w = tid >> 6;
    const int rowi = w * 8 + (l & 7);
    const int p = l >> 3;                        // 0..7
    const int grow = row0 + rowi;
    const int tb = grow & (T_ - 1);              // t within its batch row
    float s = 0.f;
    #pragma unroll
    for (int cc = 0; cc < 8; ++cc) {
      const int c = p * 32 + cc * 4;
      float4 x0 = *(const float4*)&sm[XS_OFF + rowi * XS_P + c];
      float4 xm, xp;
      if (tb == 0)             xm = make_float4(0.f, 0.f, 0.f, 0.f);
      else if (rowi >= 1)      xm = *(const float4*)&sm[XS_OFF + (rowi - 1) * XS_P + c];
      else                     xm = *(const float4*)&X[(size_t)(grow - 1) * C_ + c];
      if (tb == T_ - 1)        xp = make_float4(0.f, 0.f, 0.f, 0.f);
      else if (rowi + 1 < TB)  xp = *(const float4*)&sm[XS_OFF + (rowi + 1) * XS_P + c];
      else                     xp = *(const float4*)&X[(size_t)(grow + 1) * C_ + c];
      // conv_w flat layout: [c][k], k=0->x[t-1], 1->x[t], 2->x[t+1]
      float4 wa = *(const float4*)&CW[c * 3 + 0];
      float4 wb = *(const float4*)&CW[c * 3 + 4];
      float4 wc = *(const float4*)&CW[c * 3 + 8];
      s += xm.x * wa.x + x0.x * wa.y + xp.x * wa.z;
      s += xm.y * wa.w + x0.y * wb.x + xp.y * wb.y;
      s += xm.z * wb.z + x0.z * wb.w + xp.z * wc.x;
      s += xm.w * wc.y + x0.w * wc.z + xp.w * wc.w;
    }
    s += __shfl_xor(s, 8);
    s += __shfl_xor(s, 16);
    s += __shfl_xor(s, 32);
    if (p == 0) out[TS_OFF + grow] = 1.f / (1.f + expf(-(s + CB[0])));
  }

  // ---- GEMM1: (32x256)@(256x128), 4x4 per thread.
  //      A: X tile in LDS (broadcast reads). B: W1 in 32-row chunks,
  //      global->reg->LDS staging with 1-chunk-ahead prefetch. ----
  const int rt = tid >> 5, ct = tid & 31;   // 8 row-groups x 32 col-groups
  const int rb = rt * 4;
  float4 acc0 = make_float4(0.f, 0.f, 0.f, 0.f);
  float4 acc1 = acc0, acc2 = acc0, acc3 = acc0;
  for (int kc = 0; kc < 8; ++kc) {
    // write staged chunk to LDS
    *(float4*)&sm[W1S_OFF + 0 * 1024 + tid * 4] = st0;
    *(float4*)&sm[W1S_OFF + 1 * 1024 + tid * 4] = st1;
    *(float4*)&sm[W1S_OFF + 2 * 1024 + tid * 4] = st2;
    *(float4*)&sm[W1S_OFF + 3 * 1024 + tid * 4] = st3;
    __syncthreads();
    if (kc + 1 < 8) {   // prefetch next chunk; latency hidden under compute
      const float* wp = W1 + (size_t)(kc + 1) * 4096;
      st0 = *(const float4*)&wp[0 * 1024 + tid * 4];
      st1 = *(const float4*)&wp[1 * 1024 + tid * 4];
      st2 = *(const float4*)&wp[2 * 1024 + tid * 4];
      st3 = *(const float4*)&wp[3 * 1024 + tid * 4];
    }
    #pragma unroll
    for (int k4 = 0; k4 < 8; ++k4) {
      const int kb = kc * 32 + k4 * 4;
      float4 a0 = *(const float4*)&sm[XS_OFF + (rb + 0) * XS_P + kb];
      float4 a1 = *(const float4*)&sm[XS_OFF + (rb + 1) * XS_P + kb];
      float4 a2 = *(const float4*)&sm[XS_OFF + (rb + 2) * XS_P + kb];
      float4 a3 = *(const float4*)&sm[XS_OFF + (rb + 3) * XS_P + kb];
      float4 q0 = *(const float4*)&sm[W1S_OFF + (k4 * 4 + 0) * H1_ + ct * 4];
      float4 q1 = *(const float4*)&sm[W1S_OFF + (k4 * 4 + 1) * H1_ + ct * 4];
      float4 q2 = *(const float4*)&sm[W1S_OFF + (k4 * 4 + 2) * H1_ + ct * 4];
      float4 q3 = *(const float4*)&sm[W1S_OFF + (k4 * 4 + 3) * H1_ + ct * 4];
      fma4(acc0, a0.x, q0); fma4(acc0, a0.y, q1); fma4(acc0, a0.z, q2); fma4(acc0, a0.w, q3);
      fma4(acc1, a1.x, q0); fma4(acc1, a1.y, q1); fma4(acc1, a1.z, q2); fma4(acc1, a1.w, q3);
      fma4(acc2, a2.x, q0); fma4(acc2, a2.y, q1); fma4(acc2, a2.z, q2); fma4(acc2, a2.w, q3);
      fma4(acc3, a3.x, q0); fma4(acc3, a3.y, q1); fma4(acc3, a3.z, q2); fma4(acc3, a3.w, q3);
    }
    __syncthreads();   // all reads of this chunk done before next write
  }

  // ---- bias+relu -> H1s (overlays W1S; XS now dead too) ----
  {
    float4 bb = *(const float4*)&b1[ct * 4];
    float4 h;
    h = acc0; h.x = fmaxf(h.x + bb.x, 0.f); h.y = fmaxf(h.y + bb.y, 0.f);
              h.z = fmaxf(h.z + bb.z, 0.f); h.w = fmaxf(h.w + bb.w, 0.f);
    *(float4*)&sm[H1S_OFF + (rb + 0) * H1S_P + ct * 4] = h;
    h = acc1; h.x = fmaxf(h.x + bb.x, 0.f); h.y = fmaxf(h.y + bb.y, 0.f);
              h.z = fmaxf(h.z + bb.z, 0.f); h.w = fmaxf(h.w + bb.w, 0.f);
    *(float4*)&sm[H1S_OFF + (rb + 1) * H1S_P + ct * 4] = h;
    h = acc2; h.x = fmaxf(h.x + bb.x, 0.f); h.y = fmaxf(h.y + bb.y, 0.f);
              h.z = fmaxf(h.z + bb.z, 0.f); h.w = fmaxf(h.w + bb.w, 0.f);
    *(float4*)&sm[H1S_OFF + (rb + 2) * H1S_P + ct * 4] = h;
    h = acc3; h.x = fmaxf(h.x + bb.x, 0.f); h.y = fmaxf(h.y + bb.y, 0.f);
              h.z = fmaxf(h.z + bb.z, 0.f); h.w = fmaxf(h.w + bb.w, 0.f);
    *(float4*)&sm[H1S_OFF + (rb + 3) * H1S_P + ct * 4] = h;
  }
  __syncthreads();

  // ---- GEMM2: (32x128)@(128x64), 2x4 per thread.
  //      A: H1 LDS broadcast. B: W2 from global (L2-hot) with 1-deep prefetch. ----
  {
    const int rt2 = tid >> 4, ct2 = tid & 15;
    const float* w2p = W2 + ct2 * 4;
    float4 Wc0 = *(const float4*)&w2p[0 * H2_];
    float4 Wc1 = *(const float4*)&w2p[1 * H2_];
    float4 Wc2 = *(const float4*)&w2p[2 * H2_];
    float4 Wc3 = *(const float4*)&w2p[3 * H2_];
    float4 c0 = make_float4(0.f, 0.f, 0.f, 0.f), c1 = c0;
    #pragma unroll
    for (int k4 = 0; k4 < 32; ++k4) {
      const int rn = (k4 < 31) ? (k4 + 1) * 4 : k4 * 4;  // guard: last reloads
      float4 Wn0 = *(const float4*)&w2p[(rn + 0) * H2_];
      float4 Wn1 = *(const float4*)&w2p[(rn + 1) * H2_];
      float4 Wn2 = *(const float4*)&w2p[(rn + 2) * H2_];
      float4 Wn3 = *(const float4*)&w2p[(rn + 3) * H2_];
      float4 a0 = *(const float4*)&sm[H1S_OFF + (rt2 * 2 + 0) * H1S_P + k4 * 4];
      float4 a1 = *(const float4*)&sm[H1S_OFF + (rt2 * 2 + 1) * H1S_P + k4 * 4];
      fma4(c0, a0.x, Wc0); fma4(c0, a0.y, Wc1); fma4(c0, a0.z, Wc2); fma4(c0, a0.w, Wc3);
      fma4(c1, a1.x, Wc0); fma4(c1, a1.y, Wc1); fma4(c1, a1.z, Wc2); fma4(c1, a1.w, Wc3);
      Wc0 = Wn0; Wc1 = Wn1; Wc2 = Wn2; Wc3 = Wn3;
    }
    float4 bb = *(const float4*)&b2[ct2 * 4];
    c0.x = fmaxf(c0.x + bb.x, 0.f); c0.y = fmaxf(c0.y + bb.y, 0.f);
    c0.z = fmaxf(c0.z + bb.z, 0.f); c0.w = fmaxf(c0.w + bb.w, 0.f);
    c1.x = fmaxf(c1.x + bb.x, 0.f); c1.y = fmaxf(c1.y + bb.y, 0.f);
    c1.z = fmaxf(c1.z + bb.z, 0.f); c1.w = fmaxf(c1.w + bb.w, 0.f);
    *(float4*)&sm[H2S_OFF + (rt2 * 2 + 0) * H2S_P + ct2 * 4] = c0;
    *(float4*)&sm[H2S_OFF + (rt2 * 2 + 1) * H2S_P + ct2 * 4] = c1;
  }
  { // W3 (64x4) -> W3T[4][64]  (XS region is dead; safe overlay)
    int k = tid >> 2, j = tid & 3;
    sm[W3S_OFF + j * W3S_P + k] = W3[tid];
  }
  __syncthreads();

  // ---- GEMM3 (64->4) + softmax + dom/conf ----
  if (tid < 128) {
    const int row = tid >> 2, j = tid & 3;
    float4 ps = make_float4(0.f, 0.f, 0.f, 0.f);
    #pragma unroll
    for (int k4 = 0; k4 < 16; ++k4) {
      float4 a = *(const float4*)&sm[H2S_OFF + row * H2S_P + k4 * 4];
      float4 w = *(const float4*)&sm[W3S_OFF + j * W3S_P + k4 * 4];
      ps.x = fmaf(a.x, w.x, ps.x);
      ps.y = fmaf(a.y, w.y, ps.y);
      ps.z = fmaf(a.z, w.z, ps.z);
      ps.w = fmaf(a.w, w.w, ps.w);
    }
    float l = ((ps.x + ps.y) + (ps.z + ps.w)) + b3[j];
    float n1v = __shfl_xor(l, 1);
    float n2v = __shfl_xor(l, 2);
    float n3v = __shfl_xor(l, 3);
    // reconstruct logits indexed 0..3 (value at index i came from lane j^m, m=i^j)
    float L0 = (j == 0) ? l : (j == 1) ? n1v : (j == 2) ? n2v : n3v;
    float L1 = (j == 1) ? l : (j == 0) ? n1v : (j == 2) ? n3v : n2v;
    float L2 = (j == 2) ? l : (j == 0) ? n2v : (j == 1) ? n3v : n1v;
    float L3 = (j == 3) ? l : (j == 0) ? n3v : (j == 1) ? n2v : n1v;
    float mx = fmaxf(fmaxf(L0, L1), fmaxf(L2, L3));
    float e0 = expf(L0 - mx), e1 = expf(L1 - mx), e2 = expf(L2 - mx), e3 = expf(L3 - mx);
    float inv = 1.f / ((e0 + e1) + (e2 + e3));
    float p0 = e0 * inv, p1 = e1 * inv, p2 = e2 * inv, p3 = e3 * inv;
    const int grow = row0 + row;
    float pown = (j == 0) ? p0 : (j == 1) ? p1 : (j == 2) ? p2 : p3;
    out[PROBS_OFF + (size_t)grow * 4 + j] = pown;
    if (j == 0) {
      int dom = 0; float pm = p0;
      if (p1 > pm) { pm = p1; dom = 1; }
      if (p2 > pm) { pm = p2; dom = 2; }
      if (p3 > pm) { pm = p3; dom = 3; }
      out[MI_OFF + grow] = (float)dom;   // park dom for kernel 2
      out[MC_OFF + grow] = pm;           // park conf for kernel 2
    }
  }
}

// ---- kernel 2: per-batch-row segmentation + segment means ----
__global__ __launch_bounds__(1024, 1) void seg_kernel(
    const float* __restrict__ inten, float* __restrict__ out)
{
  __shared__ float scnt[T_], ssi[T_], ssc[T_];
  __shared__ int wtot[16], wexcl[16];
  const int tid = threadIdx.x;
  const int lane = tid & 63, wid = tid >> 6;
  const size_t base = (size_t)blockIdx.x * T_;
  const float* tsS = out + TS_OFF;
  float* segO = out + SEG_OFF;
  float* miO  = out + MI_OFF;
  float* mcO  = out + MC_OFF;
  const int t4 = tid * 4;

  float4 dv = *(const float4*)&miO[base + t4];        // dom (as float)
  float4 tv = *(const float4*)&tsS[base + t4];        // transition scores
  float4 iv = *(const float4*)&inten[base + t4];      // intensity
  float4 cv = *(const float4*)&mcO[base + t4];        // confidence
  float pd = (tid == 0) ? 0.f : miO[base + t4 - 1];

  for (int i = tid; i < T_; i += 1024) { scnt[i] = 0.f; ssi[i] = 0.f; ssc[i] = 0.f; }

  int c0 = (t4 == 0) ? 0 : (((dv.x != pd)   || (tv.x > 0.7f)) ? 1 : 0);
  int c1 = ((dv.y != dv.x) || (tv.y > 0.7f)) ? 1 : 0;
  int c2 = ((dv.z != dv.y) || (tv.z > 0.7f)) ? 1 : 0;
  int c3 = ((dv.w != dv.z) || (tv.w > 0.7f)) ? 1 : 0;
  int l0 = c0, l1 = c0 + c1, l2 = l1 + c2, l3 = l2 + c3;
  const int tsum = l3;

  // wave-inclusive scan of per-thread sums
  int v = tsum;
  #pragma unroll
  for (int d = 1; d < 64; d <<= 1) {
    int o = __shfl_up(v, (unsigned)d);
    if (lane >= d) v += o;
  }
  if (lane == 63) wtot[wid] = v;
  __syncthreads();
  if (tid < 16) {
    int x = wtot[tid];
    int xx = x;
    #pragma unroll
    for (int d = 1; d < 16; d <<= 1) {
      int o = __shfl_up(xx, (unsigned)d);
      if (tid >= d) xx += o;
    }
    wexcl[tid] = xx - x;   // exclusive wave offset
  }
  __syncthreads();
  const int texcl = wexcl[wid] + (v - tsum);
  const int s0 = texcl + l0, s1 = texcl + l1, s2 = texcl + l2, s3 = texcl + l3;

  // merged LDS atomics for segment sums
  {
    int cur = s0; float aI = iv.x, aC = cv.x, aN = 1.f;
    if (s1 == cur) { aI += iv.y; aC += cv.y; aN += 1.f; }
    else { atomicAdd(&ssi[cur], aI); atomicAdd(&ssc[cur], aC); atomicAdd(&scnt[cur], aN);
           cur = s1; aI = iv.y; aC = cv.y; aN = 1.f; }
    if (s2 == cur) { aI += iv.z; aC += cv.z; aN += 1.f; }
    else { atomicAdd(&ssi[cur], aI); atomicAdd(&ssc[cur], aC); atomicAdd(&scnt[cur], aN);
           cur = s2; aI = iv.z; aC = cv.z; aN = 1.f; }
    if (s3 == cur) { aI += iv.w; aC += cv.w; aN += 1.f; }
    else { atomicAdd(&ssi[cur], aI); atomicAdd(&ssc[cur], aC); atomicAdd(&scnt[cur], aN);
           cur = s3; aI = iv.w; aC = cv.w; aN = 1.f; }
    atomicAdd(&ssi[cur], aI); atomicAdd(&ssc[cur], aC); atomicAdd(&scnt[cur], aN);
  }
  __syncthreads();

  float n0 = scnt[s0], n1 = scnt[s1], n2 = scnt[s2], n3 = scnt[s3];
  float4 m4, q4, g4;
  m4.x = ssi[s0] / n0; m4.y = ssi[s1] / n1; m4.z = ssi[s2] / n2; m4.w = ssi[s3] / n3;
  q4.x = ssc[s0] / n0; q4.y = ssc[s1] / n1; q4.z = ssc[s2] / n2; q4.w = ssc[s3] / n3;
  g4.x = (float)s0; g4.y = (float)s1; g4.z = (float)s2; g4.w = (float)s3;
  *(float4*)&segO[base + t4] = g4;
  *(float4*)&miO[base + t4]  = m4;
  *(float4*)&mcO[base + t4]  = q4;
}

extern "C" void kernel_launch(void* const* d_in, const int* in_sizes, int n_in,
                              void* d_out, int out_size, void* d_ws, size_t ws_size,
                              hipStream_t stream) {
  (void)in_sizes; (void)n_in; (void)out_size; (void)d_ws; (void)ws_size;
  const float* X   = (const float*)d_in[0];
  const float* INT = (const float*)d_in[1];
  const float* W1  = (const float*)d_in[2];
  const float* B1  = (const float*)d_in[3];
  const float* W2  = (const float*)d_in[4];
  const float* B2  = (const float*)d_in[5];
  const float* W3  = (const float*)d_in[6];
  const float* B3  = (const float*)d_in[7];
  const float* CW  = (const float*)d_in[8];
  const float* CB  = (const float*)d_in[9];
  float* out = (float*)d_out;

  hipLaunchKernelGGL(mlp_conv_kernel, dim3(R_ / TB), dim3(256), 0, stream,
                     X, W1, B1, W2, B2, W3, B3, CW, CB, out);
  hipLaunchKernelGGL(seg_kernel, dim3(B_), dim3(1024), 0, stream, INT, out);
}